// Round 1
// baseline (453.393 us; speedup 1.0000x reference)
//
#include <hip/hip_runtime.h>

#define DH 1024
#define FH 2752
#define NE 8
#define NT 1024   // tokens = 2*512

typedef unsigned short u16;
typedef __bf16 bf16x8 __attribute__((ext_vector_type(8)));
typedef u16 u16x8 __attribute__((ext_vector_type(8)));
typedef float f32x4 __attribute__((ext_vector_type(4)));

__device__ __forceinline__ u16 f2bf(float f) {
  unsigned int u = __float_as_uint(f);
  unsigned int r = (u + 0x7fffu + ((u >> 16) & 1u)) >> 16;
  return (u16)r;
}
__device__ __forceinline__ float bf2f(u16 b) {
  return __uint_as_float(((unsigned int)b) << 16);
}

// ---------------- 1. gating: logits, top-2, softmax, x -> bf16 ----------------
__global__ void gate_kernel(const float* __restrict__ x,
                            const float* __restrict__ Ws,
                            const float* __restrict__ bs,
                            u16* __restrict__ xb,
                            int* __restrict__ tki,
                            float* __restrict__ tkw) {
  int gtid = blockIdx.x * blockDim.x + threadIdx.x;
  int t = gtid >> 6;
  int lane = gtid & 63;
  if (t >= NT) return;
  const float* xr = x + (size_t)t * DH;
  float acc[NE];
#pragma unroll
  for (int e = 0; e < NE; ++e) acc[e] = 0.f;
  for (int d = lane; d < DH; d += 64) {
    float xv = xr[d];
    xb[(size_t)t * DH + d] = f2bf(xv);
    const float4* wr = (const float4*)(Ws + (size_t)d * NE);
    float4 w0 = wr[0], w1 = wr[1];
    acc[0] += xv * w0.x; acc[1] += xv * w0.y;
    acc[2] += xv * w0.z; acc[3] += xv * w0.w;
    acc[4] += xv * w1.x; acc[5] += xv * w1.y;
    acc[6] += xv * w1.z; acc[7] += xv * w1.w;
  }
#pragma unroll
  for (int e = 0; e < NE; ++e) {
#pragma unroll
    for (int off = 32; off > 0; off >>= 1)
      acc[e] += __shfl_xor(acc[e], off);
  }
  if (lane == 0) {
    float l[NE];
#pragma unroll
    for (int e = 0; e < NE; ++e) l[e] = acc[e] + bs[e];
    int i0 = 0;
#pragma unroll
    for (int e = 1; e < NE; ++e) if (l[e] > l[i0]) i0 = e;
    int i1 = (i0 == 0) ? 1 : 0;
#pragma unroll
    for (int e = 0; e < NE; ++e) if (e != i0 && l[e] > l[i1]) i1 = e;
    float e1 = __expf(l[i1] - l[i0]);
    float denom = 1.f + e1;
    tki[t*2]   = i0; tki[t*2+1] = i1;
    tkw[t*2]   = 1.f / denom;
    tkw[t*2+1] = e1 / denom;
  }
}

// ---------------- 2. expert grouping ----------------
__global__ void group_kernel(const int* __restrict__ tki,
                             int* __restrict__ offs,
                             int* __restrict__ rtok,
                             int* __restrict__ posf) {
  __shared__ int cnt[NE];
  __shared__ int run[NE];
  int tid = threadIdx.x;
  if (tid < NE) cnt[tid] = 0;
  __syncthreads();
  for (int t = tid; t < NT; t += blockDim.x) {
    atomicAdd(&cnt[tki[t*2]], 1);
    atomicAdd(&cnt[tki[t*2+1]], 1);
  }
  __syncthreads();
  if (tid == 0) {
    int r = 0;
    for (int e = 0; e < NE; ++e) { offs[e] = r; run[e] = r; r += cnt[e]; }
    offs[NE] = r;   // == 2048
  }
  __syncthreads();
  for (int t = tid; t < NT; t += blockDim.x) {
    for (int k = 0; k < 2; ++k) {
      int e = tki[t*2+k];
      int p = atomicAdd(&run[e], 1);
      rtok[p] = t;
      posf[t*2+k] = p;
    }
  }
}

// ---------------- 3. grouped GEMM (A bf16 [rows,K], B fp32 [E][K][N]) ----------------
// BM=256, BK=32, 4 waves; each wave computes 64 rows x BN cols via 16x16x32 MFMA.
template<int BN, bool GATHER, bool OUT_BF16>
__global__ __launch_bounds__(256)
void gemm_kernel(const u16* __restrict__ A,
                 const float* __restrict__ B,
                 void* __restrict__ outp,
                 const int* __restrict__ offs,
                 const int* __restrict__ rtok,
                 int Ksz, int Nsz, int Arow) {
  constexpr int BM = 256;
  constexpr int BK = 32;
  constexpr int NF = BN / 16;
  constexpr int PAD = 8;
  __shared__ u16 a_sm[BM][BK + PAD];
  __shared__ u16 b_sm[BN][BK + PAD];

  int e  = blockIdx.z;
  int mt = blockIdx.y;
  int nt = blockIdx.x;
  int off0 = offs[e];
  int cnt  = offs[e+1] - off0;
  if (mt * BM >= cnt) return;
  int p0 = off0 + mt * BM;
  int n0 = nt * BN;
  int tid = threadIdx.x;

  // A staging: thread r stages row r (32 bf16 = 4x int4)
  int r = tid;
  bool avalid = (mt * BM + r) < cnt;
  const u16* asrc = nullptr;
  if (avalid) {
    int arow_idx = GATHER ? rtok[p0 + r] : (p0 + r);
    asrc = A + (size_t)arow_idx * Arow;
  }
  const float* bbase = B + (size_t)e * Ksz * Nsz + n0;

  f32x4 acc[4][NF];
#pragma unroll
  for (int mf = 0; mf < 4; ++mf)
#pragma unroll
    for (int nf = 0; nf < NF; ++nf)
      acc[mf][nf] = f32x4{0.f, 0.f, 0.f, 0.f};

  int lane = tid & 63;
  int wv   = tid >> 6;
  int arow0 = wv * 64 + (lane & 15);
  int kg    = (lane >> 4) * 8;

  constexpr int ELEMS = BN * BK / 256;   // 8 (BN=64) or 4 (BN=32)
  int kl = tid >> 3;            // 0..31 : k row within tile
  int nc = (tid & 7) * ELEMS;   // n chunk

  for (int kt = 0; kt < Ksz; kt += BK) {
    if (avalid) {
#pragma unroll
      for (int j = 0; j < 4; ++j)
        *(int4*)&a_sm[r][j*8] = *(const int4*)(asrc + kt + j*8);
    } else {
      int4 z = {0,0,0,0};
#pragma unroll
      for (int j = 0; j < 4; ++j)
        *(int4*)&a_sm[r][j*8] = z;
    }
    const float* bsrc = bbase + (size_t)(kt + kl) * Nsz + nc;
#pragma unroll
    for (int i = 0; i < ELEMS; i += 4) {
      float4 v = *(const float4*)(bsrc + i);
      b_sm[nc+i+0][kl] = f2bf(v.x);
      b_sm[nc+i+1][kl] = f2bf(v.y);
      b_sm[nc+i+2][kl] = f2bf(v.z);
      b_sm[nc+i+3][kl] = f2bf(v.w);
    }
    __syncthreads();

    bf16x8 af[4], bfr[NF];
#pragma unroll
    for (int mf = 0; mf < 4; ++mf)
      af[mf] = *(const bf16x8*)&a_sm[arow0 + mf*16][kg];
#pragma unroll
    for (int nf = 0; nf < NF; ++nf)
      bfr[nf] = *(const bf16x8*)&b_sm[nf*16 + (lane & 15)][kg];
#pragma unroll
    for (int mf = 0; mf < 4; ++mf)
#pragma unroll
      for (int nf = 0; nf < NF; ++nf)
        acc[mf][nf] = __builtin_amdgcn_mfma_f32_16x16x32_bf16(af[mf], bfr[nf], acc[mf][nf], 0, 0, 0);
    __syncthreads();
  }

  // epilogue: D layout col = lane&15, row = (lane>>4)*4 + q
  int rb = wv * 64 + (lane >> 4) * 4;
#pragma unroll
  for (int mf = 0; mf < 4; ++mf) {
#pragma unroll
    for (int nf = 0; nf < NF; ++nf) {
      int col = n0 + nf*16 + (lane & 15);
#pragma unroll
      for (int q = 0; q < 4; ++q) {
        int lrow = mt*BM + rb + mf*16 + q;
        if (lrow < cnt) {
          size_t oidx = (size_t)(off0 + lrow) * Nsz + col;
          if constexpr (OUT_BF16) ((u16*)outp)[oidx] = f2bf(acc[mf][nf][q]);
          else                    ((float*)outp)[oidx] = acc[mf][nf][q];
        }
      }
    }
  }
}

// ---------------- 4. swiglu: h = silu(g)*u ----------------
__global__ void swiglu_kernel(const u16* __restrict__ g,
                              const u16* __restrict__ u,
                              u16* __restrict__ h) {
  size_t i = ((size_t)blockIdx.x * blockDim.x + threadIdx.x) * 8;
  u16x8 g8 = *(const u16x8*)(g + i);
  u16x8 u8 = *(const u16x8*)(u + i);
  u16x8 o;
#pragma unroll
  for (int j = 0; j < 8; ++j) {
    float gv = bf2f(g8[j]);
    float uv = bf2f(u8[j]);
    float s  = gv / (1.f + __expf(-gv));
    o[j] = f2bf(s * uv);
  }
  *(u16x8*)(h + i) = o;
}

// ---------------- 5. combine: out[t] = w0*y[p0] + w1*y[p1] ----------------
__global__ void combine_kernel(const float* __restrict__ yb,
                               const float* __restrict__ tkw,
                               const int* __restrict__ posf,
                               float* __restrict__ out) {
  int t = blockIdx.x;
  int d = threadIdx.x;
  int pa = posf[t*2], pb = posf[t*2+1];
  float wa = tkw[t*2], wb = tkw[t*2+1];
  float4 a = ((const float4*)(yb + (size_t)pa * DH))[d];
  float4 b = ((const float4*)(yb + (size_t)pb * DH))[d];
  float4 o;
  o.x = wa*a.x + wb*b.x;
  o.y = wa*a.y + wb*b.y;
  o.z = wa*a.z + wb*b.z;
  o.w = wa*a.w + wb*b.w;
  ((float4*)(out + (size_t)t * DH))[d] = o;
}

extern "C" void kernel_launch(void* const* d_in, const int* in_sizes, int n_in,
                              void* d_out, int out_size, void* d_ws, size_t ws_size,
                              hipStream_t stream) {
  const float* x  = (const float*)d_in[0];
  const float* Ws = (const float*)d_in[1];
  const float* bs = (const float*)d_in[2];
  const float* Wg = (const float*)d_in[3];
  const float* Wu = (const float*)d_in[4];
  const float* Wd = (const float*)d_in[5];
  float* out = (float*)d_out;
  char* ws = (char*)d_ws;

  // workspace layout (bytes)
  int*   tki  = (int*)  (ws + 0);        // 1024*2 int
  float* tkw  = (float*)(ws + 8192);     // 1024*2 float
  int*   offs = (int*)  (ws + 16384);    // 9 int
  int*   posf = (int*)  (ws + 20480);    // 1024*2 int
  int*   rtok = (int*)  (ws + 28672);    // 2048 int
  u16*   xb   = (u16*)  (ws + 36864);    // 1024*1024 bf16 = 2 MB
  char*  base2 = ws + 36864 + 2097152;
  u16*   gbuf = (u16*)(base2);                    // 2048*2752 bf16 = 11.27 MB
  u16*   ubuf = (u16*)(base2 + 11272192);         // 11.27 MB
  u16*   hbuf = (u16*)(base2 + 2*11272192);       // 11.27 MB
  float* yb   = (float*)(base2);                  // reuse g region: 2048*1024 f32 = 8 MB

  gate_kernel<<<256, 256, 0, stream>>>(x, Ws, bs, xb, tki, tkw);
  group_kernel<<<1, 256, 0, stream>>>(tki, offs, rtok, posf);
  // gate & up projections: A = gathered xb rows, B = Wg/Wu [D][F]
  gemm_kernel<64, true, true><<<dim3(FH/64, 4, NE), 256, 0, stream>>>(
      xb, Wg, gbuf, offs, rtok, DH, FH, DH);
  gemm_kernel<64, true, true><<<dim3(FH/64, 4, NE), 256, 0, stream>>>(
      xb, Wu, ubuf, offs, rtok, DH, FH, DH);
  swiglu_kernel<<<(2048*FH/8)/256, 256, 0, stream>>>(gbuf, ubuf, hbuf);
  // down projection: A = h rows (already grouped), B = Wd [F][D]
  gemm_kernel<32, false, false><<<dim3(DH/32, 4, NE), 256, 0, stream>>>(
      hbuf, Wd, yb, offs, rtok, FH, DH, FH);
  combine_kernel<<<NT, 256, 0, stream>>>(yb, tkw, posf, out);
}

// Round 2
// 185.536 us; speedup vs baseline: 2.4437x; 2.4437x over previous
//
#include <hip/hip_runtime.h>

#define DH 1024
#define FH 2752
#define NE 8
#define NT 1024
#define BM 256
#define BKF 64
#define BNF 32

typedef unsigned short u16;
typedef __bf16 bf16x8 __attribute__((ext_vector_type(8)));
typedef u16 u16x8 __attribute__((ext_vector_type(8)));
typedef float f32x4 __attribute__((ext_vector_type(4)));

__device__ __forceinline__ u16 f2bf(float f) {
  unsigned int u = __float_as_uint(f);
  unsigned int r = (u + 0x7fffu + ((u >> 16) & 1u)) >> 16;
  return (u16)r;
}
__device__ __forceinline__ float bf2f(u16 b) {
  return __uint_as_float(((unsigned int)b) << 16);
}
__device__ __forceinline__ bf16x8 as_bf(int4 v) {
  union { int4 i; bf16x8 b; } u; u.i = v; return u.b;
}
__device__ __forceinline__ bf16x8 as_bfu(u16x8 v) {
  union { u16x8 u; bf16x8 b; } x; x.u = v; return x.b;
}

// ---------------- 1. gating ----------------
__global__ void gate_kernel(const float* __restrict__ x,
                            const float* __restrict__ Ws,
                            const float* __restrict__ bs,
                            u16* __restrict__ xb,
                            int* __restrict__ tki,
                            float* __restrict__ tkw) {
  int gtid = blockIdx.x * blockDim.x + threadIdx.x;
  int t = gtid >> 6;
  int lane = gtid & 63;
  if (t >= NT) return;
  const float* xr = x + (size_t)t * DH;
  float acc[NE];
#pragma unroll
  for (int e = 0; e < NE; ++e) acc[e] = 0.f;
  for (int d = lane; d < DH; d += 64) {
    float xv = xr[d];
    xb[(size_t)t * DH + d] = f2bf(xv);
    const float4* wr = (const float4*)(Ws + (size_t)d * NE);
    float4 w0 = wr[0], w1 = wr[1];
    acc[0] += xv * w0.x; acc[1] += xv * w0.y;
    acc[2] += xv * w0.z; acc[3] += xv * w0.w;
    acc[4] += xv * w1.x; acc[5] += xv * w1.y;
    acc[6] += xv * w1.z; acc[7] += xv * w1.w;
  }
#pragma unroll
  for (int e = 0; e < NE; ++e) {
#pragma unroll
    for (int off = 32; off > 0; off >>= 1)
      acc[e] += __shfl_xor(acc[e], off);
  }
  if (lane == 0) {
    float l[NE];
#pragma unroll
    for (int e = 0; e < NE; ++e) l[e] = acc[e] + bs[e];
    int i0 = 0;
#pragma unroll
    for (int e = 1; e < NE; ++e) if (l[e] > l[i0]) i0 = e;
    int i1 = (i0 == 0) ? 1 : 0;
#pragma unroll
    for (int e = 0; e < NE; ++e) if (e != i0 && l[e] > l[i1]) i1 = e;
    float e1 = __expf(l[i1] - l[i0]);
    float denom = 1.f + e1;
    tki[t*2]   = i0; tki[t*2+1] = i1;
    tkw[t*2]   = 1.f / denom;
    tkw[t*2+1] = e1 / denom;
  }
}

// ---------------- 2. expert grouping ----------------
__global__ void group_kernel(const int* __restrict__ tki,
                             int* __restrict__ offs,
                             int* __restrict__ rtok,
                             int* __restrict__ posf) {
  __shared__ int cnt[NE];
  __shared__ int run[NE];
  int tid = threadIdx.x;
  if (tid < NE) cnt[tid] = 0;
  __syncthreads();
  for (int t = tid; t < NT; t += blockDim.x) {
    atomicAdd(&cnt[tki[t*2]], 1);
    atomicAdd(&cnt[tki[t*2+1]], 1);
  }
  __syncthreads();
  if (tid == 0) {
    int r = 0;
    for (int e = 0; e < NE; ++e) { offs[e] = r; run[e] = r; r += cnt[e]; }
    offs[NE] = r;
  }
  __syncthreads();
  for (int t = tid; t < NT; t += blockDim.x) {
    for (int k = 0; k < 2; ++k) {
      int e = tki[t*2+k];
      int p = atomicAdd(&run[e], 1);
      rtok[p] = t;
      posf[t*2+k] = p;
    }
  }
}

// ---------------- 3. fused gate+up+SwiGLU GEMM ----------------
// BM=256 rows x BN=32 cols per block, BK=64, 4 waves.
// A direct global->reg (prefetched), B (Wg & Wu) f32->bf16 double-buffered LDS.
#define GU_BODY(ACUR, ANXT, CUR, IT)                                          \
  {                                                                           \
    if ((IT) + 1 < 16) {                                                      \
      _Pragma("unroll") for (int h = 0; h < 2; ++h)                           \
      _Pragma("unroll") for (int i = 0; i < 4; ++i) {                         \
        bg_sm[(CUR)^1][ncB + i][klA + h] = f2bf(sg[h][i]);                    \
        bu_sm[(CUR)^1][ncB + i][klA + h] = f2bf(su[h][i]);                    \
      }                                                                       \
    }                                                                         \
    if ((IT) + 2 < 16) {                                                      \
      const float* g2 = gsrc + (size_t)((IT)+2) * BKF * FH;                   \
      const float* u2 = usrc + (size_t)((IT)+2) * BKF * FH;                   \
      sg[0] = *(const f32x4*)(g2);  sg[1] = *(const f32x4*)(g2 + FH);         \
      su[0] = *(const f32x4*)(u2);  su[1] = *(const f32x4*)(u2 + FH);         \
    }                                                                         \
    if ((IT) + 1 < 16) {                                                      \
      _Pragma("unroll") for (int mf = 0; mf < 4; ++mf) {                      \
        const u16* ap = aptr[mf] + ((IT)+1) * BKF;                            \
        ANXT[mf][0] = *(const int4*)(ap);                                     \
        ANXT[mf][1] = *(const int4*)(ap + 32);                                \
      }                                                                       \
    }                                                                         \
    _Pragma("unroll") for (int h = 0; h < 2; ++h) {                           \
      u16x8 fg0 = *(const u16x8*)&bg_sm[CUR][(lane&15)][h*32 + kg];           \
      u16x8 fg1 = *(const u16x8*)&bg_sm[CUR][16 + (lane&15)][h*32 + kg];      \
      u16x8 fu0 = *(const u16x8*)&bu_sm[CUR][(lane&15)][h*32 + kg];           \
      u16x8 fu1 = *(const u16x8*)&bu_sm[CUR][16 + (lane&15)][h*32 + kg];      \
      _Pragma("unroll") for (int mf = 0; mf < 4; ++mf) {                      \
        bf16x8 av = as_bf(ACUR[mf][h]);                                       \
        accg[mf][0] = __builtin_amdgcn_mfma_f32_16x16x32_bf16(av, as_bfu(fg0), accg[mf][0], 0,0,0); \
        accg[mf][1] = __builtin_amdgcn_mfma_f32_16x16x32_bf16(av, as_bfu(fg1), accg[mf][1], 0,0,0); \
        accu[mf][0] = __builtin_amdgcn_mfma_f32_16x16x32_bf16(av, as_bfu(fu0), accu[mf][0], 0,0,0); \
        accu[mf][1] = __builtin_amdgcn_mfma_f32_16x16x32_bf16(av, as_bfu(fu1), accu[mf][1], 0,0,0); \
      }                                                                       \
    }                                                                         \
    __syncthreads();                                                          \
  }

__global__ __launch_bounds__(256, 2)
void gu_kernel(const u16* __restrict__ xb,
               const float* __restrict__ Wg,
               const float* __restrict__ Wu,
               u16* __restrict__ hbuf,
               const int* __restrict__ offs,
               const int* __restrict__ rtok) {
  __shared__ u16 bg_sm[2][BNF][BKF + 8];
  __shared__ u16 bu_sm[2][BNF][BKF + 8];

  int e  = blockIdx.z;
  int mt = blockIdx.y;
  int nt = blockIdx.x;
  int off0 = offs[e];
  int cnt  = offs[e+1] - off0;
  if (cnt <= 0 || mt * BM >= cnt) return;
  int p0 = off0 + mt * BM;
  int rmax = cnt - mt * BM - 1;
  int n0 = nt * BNF;
  int tid = threadIdx.x;
  int lane = tid & 63, wv = tid >> 6;
  int kg = (lane >> 4) * 8;

  const u16* aptr[4];
#pragma unroll
  for (int mf = 0; mf < 4; ++mf) {
    int lrow = wv*64 + (lane & 15) + mf*16;
    int tok = rtok[p0 + (lrow > rmax ? rmax : lrow)];
    aptr[mf] = xb + (size_t)tok * DH + kg;
  }

  int klA = (tid >> 3) * 2;
  int ncB = (tid & 7) * 4;
  const float* gsrc = Wg + (size_t)e * DH * FH + (size_t)klA * FH + n0 + ncB;
  const float* usrc = Wu + (size_t)e * DH * FH + (size_t)klA * FH + n0 + ncB;

  f32x4 accg[4][2], accu[4][2];
#pragma unroll
  for (int mf = 0; mf < 4; ++mf)
#pragma unroll
    for (int nf = 0; nf < 2; ++nf) {
      accg[mf][nf] = f32x4{0.f,0.f,0.f,0.f};
      accu[mf][nf] = f32x4{0.f,0.f,0.f,0.f};
    }

  int4 a0[4][2], a1[4][2];
  f32x4 sg[2], su[2];

  // prologue: B(0) + A(0), stage B(0) into LDS[0], issue B(1)
  sg[0] = *(const f32x4*)(gsrc);  sg[1] = *(const f32x4*)(gsrc + FH);
  su[0] = *(const f32x4*)(usrc);  su[1] = *(const f32x4*)(usrc + FH);
#pragma unroll
  for (int mf = 0; mf < 4; ++mf) {
    a0[mf][0] = *(const int4*)(aptr[mf]);
    a0[mf][1] = *(const int4*)(aptr[mf] + 32);
  }
#pragma unroll
  for (int h = 0; h < 2; ++h)
#pragma unroll
    for (int i = 0; i < 4; ++i) {
      bg_sm[0][ncB + i][klA + h] = f2bf(sg[h][i]);
      bu_sm[0][ncB + i][klA + h] = f2bf(su[h][i]);
    }
  {
    const float* g1 = gsrc + (size_t)BKF * FH;
    const float* u1 = usrc + (size_t)BKF * FH;
    sg[0] = *(const f32x4*)(g1);  sg[1] = *(const f32x4*)(g1 + FH);
    su[0] = *(const f32x4*)(u1);  su[1] = *(const f32x4*)(u1 + FH);
  }
  __syncthreads();

  for (int it = 0; it < 16; it += 2) {
    GU_BODY(a0, a1, 0, it);
    GU_BODY(a1, a0, 1, (it+1));
  }

  // epilogue: h = silu(g)*u, bf16
#pragma unroll
  for (int mf = 0; mf < 4; ++mf) {
    int lr0 = wv*64 + (lane >> 4)*4 + mf*16;
#pragma unroll
    for (int nf = 0; nf < 2; ++nf) {
      int col = n0 + nf*16 + (lane & 15);
#pragma unroll
      for (int q = 0; q < 4; ++q) {
        int lrow = lr0 + q;
        if (lrow <= rmax) {
          float g = accg[mf][nf][q], u = accu[mf][nf][q];
          float s = g / (1.f + __expf(-g));
          hbuf[(size_t)(p0 + lrow) * FH + col] = f2bf(s * u);
        }
      }
    }
  }
}

// ---------------- 4. down projection with K-split=2 ----------------
#define DN_BODY(ACUR, ANXT, CUR, IT)                                          \
  {                                                                           \
    if ((IT) + 1 < nIter) {                                                   \
      _Pragma("unroll") for (int h = 0; h < 2; ++h)                           \
      _Pragma("unroll") for (int i = 0; i < 4; ++i)                           \
        b_sm[(CUR)^1][ncB + i][klA + h] = f2bf(sd[h][i]);                     \
    }                                                                         \
    if ((IT) + 2 < nIter) {                                                   \
      const float* d2 = dsrc + (size_t)((IT)+2) * BKF * DH;                   \
      sd[0] = *(const f32x4*)(d2);  sd[1] = *(const f32x4*)(d2 + DH);         \
    }                                                                         \
    if ((IT) + 1 < nIter) {                                                   \
      _Pragma("unroll") for (int mf = 0; mf < 4; ++mf) {                      \
        const u16* ap = aptr[mf] + ((IT)+1) * BKF;                            \
        ANXT[mf][0] = *(const int4*)(ap);                                     \
        ANXT[mf][1] = *(const int4*)(ap + 32);                                \
      }                                                                       \
    }                                                                         \
    _Pragma("unroll") for (int h = 0; h < 2; ++h) {                           \
      u16x8 f0 = *(const u16x8*)&b_sm[CUR][(lane&15)][h*32 + kg];             \
      u16x8 f1 = *(const u16x8*)&b_sm[CUR][16 + (lane&15)][h*32 + kg];        \
      _Pragma("unroll") for (int mf = 0; mf < 4; ++mf) {                      \
        bf16x8 av = as_bf(ACUR[mf][h]);                                       \
        acc[mf][0] = __builtin_amdgcn_mfma_f32_16x16x32_bf16(av, as_bfu(f0), acc[mf][0], 0,0,0); \
        acc[mf][1] = __builtin_amdgcn_mfma_f32_16x16x32_bf16(av, as_bfu(f1), acc[mf][1], 0,0,0); \
      }                                                                       \
    }                                                                         \
    __syncthreads();                                                          \
  }

__global__ __launch_bounds__(256, 2)
void dn_kernel(const u16* __restrict__ hb,
               const float* __restrict__ Wd,
               float* __restrict__ y,
               const int* __restrict__ offs) {
  __shared__ u16 b_sm[2][BNF][BKF + 8];

  int e  = blockIdx.z;
  int mt = blockIdx.y;
  int bx = blockIdx.x;
  int nt = bx & 31;
  int ks = bx >> 5;
  int kt0   = ks ? 1408 : 0;
  int nIter = ks ? 21 : 22;
  int off0 = offs[e];
  int cnt  = offs[e+1] - off0;
  if (cnt <= 0 || mt * BM >= cnt) return;
  int p0 = off0 + mt * BM;
  int rmax = cnt - mt * BM - 1;
  int n0 = nt * BNF;
  int tid = threadIdx.x;
  int lane = tid & 63, wv = tid >> 6;
  int kg = (lane >> 4) * 8;

  const u16* aptr[4];
#pragma unroll
  for (int mf = 0; mf < 4; ++mf) {
    int lrow = wv*64 + (lane & 15) + mf*16;
    int arow = p0 + (lrow > rmax ? rmax : lrow);
    aptr[mf] = hb + (size_t)arow * FH + kt0 + kg;
  }

  int klA = (tid >> 3) * 2;
  int ncB = (tid & 7) * 4;
  const float* dsrc = Wd + (size_t)e * FH * DH + (size_t)(kt0 + klA) * DH + n0 + ncB;

  f32x4 acc[4][2];
#pragma unroll
  for (int mf = 0; mf < 4; ++mf)
#pragma unroll
    for (int nf = 0; nf < 2; ++nf)
      acc[mf][nf] = f32x4{0.f,0.f,0.f,0.f};

  int4 a0[4][2], a1[4][2];
  f32x4 sd[2];

  sd[0] = *(const f32x4*)(dsrc);  sd[1] = *(const f32x4*)(dsrc + DH);
#pragma unroll
  for (int mf = 0; mf < 4; ++mf) {
    a0[mf][0] = *(const int4*)(aptr[mf]);
    a0[mf][1] = *(const int4*)(aptr[mf] + 32);
  }
#pragma unroll
  for (int h = 0; h < 2; ++h)
#pragma unroll
    for (int i = 0; i < 4; ++i)
      b_sm[0][ncB + i][klA + h] = f2bf(sd[h][i]);
  {
    const float* d1 = dsrc + (size_t)BKF * DH;
    sd[0] = *(const f32x4*)(d1);  sd[1] = *(const f32x4*)(d1 + DH);
  }
  __syncthreads();

  int it = 0;
  for (; it + 2 <= nIter; it += 2) {
    DN_BODY(a0, a1, 0, it);
    DN_BODY(a1, a0, 1, (it+1));
  }
  if (it < nIter) {
    DN_BODY(a0, a1, 0, it);
  }

  float* yout = y + (size_t)ks * 2048 * DH;
#pragma unroll
  for (int mf = 0; mf < 4; ++mf) {
    int lr0 = wv*64 + (lane >> 4)*4 + mf*16;
#pragma unroll
    for (int nf = 0; nf < 2; ++nf) {
      int col = n0 + nf*16 + (lane & 15);
#pragma unroll
      for (int q = 0; q < 4; ++q) {
        int lrow = lr0 + q;
        if (lrow <= rmax)
          yout[(size_t)(p0 + lrow) * DH + col] = acc[mf][nf][q];
      }
    }
  }
}

// ---------------- 5. combine ----------------
__global__ void combine_kernel(const float* __restrict__ y,
                               const float* __restrict__ tkw,
                               const int* __restrict__ posf,
                               float* __restrict__ out) {
  int t = blockIdx.x;
  int d = threadIdx.x;
  const float* y1 = y + (size_t)2048 * DH;
  int pa = posf[t*2], pb = posf[t*2+1];
  float wa = tkw[t*2], wb = tkw[t*2+1];
  f32x4 a0 = ((const f32x4*)(y  + (size_t)pa * DH))[d];
  f32x4 a1 = ((const f32x4*)(y1 + (size_t)pa * DH))[d];
  f32x4 b0 = ((const f32x4*)(y  + (size_t)pb * DH))[d];
  f32x4 b1 = ((const f32x4*)(y1 + (size_t)pb * DH))[d];
  f32x4 o;
#pragma unroll
  for (int i = 0; i < 4; ++i)
    o[i] = wa*(a0[i]+a1[i]) + wb*(b0[i]+b1[i]);
  ((f32x4*)(out + (size_t)t * DH))[d] = o;
}

extern "C" void kernel_launch(void* const* d_in, const int* in_sizes, int n_in,
                              void* d_out, int out_size, void* d_ws, size_t ws_size,
                              hipStream_t stream) {
  const float* x  = (const float*)d_in[0];
  const float* Ws = (const float*)d_in[1];
  const float* bs = (const float*)d_in[2];
  const float* Wg = (const float*)d_in[3];
  const float* Wu = (const float*)d_in[4];
  const float* Wd = (const float*)d_in[5];
  float* out = (float*)d_out;
  char* ws = (char*)d_ws;

  int*   tki  = (int*)  (ws + 0);
  float* tkw  = (float*)(ws + 8192);
  int*   offs = (int*)  (ws + 16384);
  int*   posf = (int*)  (ws + 20480);
  int*   rtok = (int*)  (ws + 28672);
  u16*   xb   = (u16*)  (ws + 36864);                 // 2 MB
  char*  base2 = ws + 36864 + 2097152;
  u16*   hbuf = (u16*)(base2);                        // 2048*2752 bf16 = 11.27 MB
  float* yws  = (float*)(base2 + 11272192);           // 2 * 2048*1024 f32 = 16 MB

  gate_kernel<<<256, 256, 0, stream>>>(x, Ws, bs, xb, tki, tkw);
  group_kernel<<<1, 256, 0, stream>>>(tki, offs, rtok, posf);
  gu_kernel<<<dim3(FH/BNF, 4, NE), 256, 0, stream>>>(xb, Wg, Wu, hbuf, offs, rtok);
  dn_kernel<<<dim3(64, 4, NE), 256, 0, stream>>>(hbuf, Wd, yws, offs);
  combine_kernel<<<NT, 256, 0, stream>>>(yws, tkw, posf, out);
}